// Round 1
// baseline (800.927 us; speedup 1.0000x reference)
//
#include <hip/hip_runtime.h>
#include <cstdint>
#include <cstddef>

#define D 256
#define E 256
#define T 128
#define QIN 640   // D + E + T
#define P 8
#define R 16      // batch rows per block

__device__ __forceinline__ float wsum(float v) {
#pragma unroll
  for (int o = 32; o > 0; o >>= 1) v += __shfl_xor(v, o, 64);
  return v;
}

__device__ __forceinline__ void wsum2(float& a, float& b) {
#pragma unroll
  for (int o = 32; o > 0; o >>= 1) {
    a += __shfl_xor(a, o, 64);
    b += __shfl_xor(b, o, 64);
  }
}

__device__ __forceinline__ float clampf(float x, float lo, float hi) {
  return fminf(fmaxf(x, lo), hi);
}

// WqT[k][d] = Wq[d][k]   (640 KB, trivial; Wq L2-resident so re-reads are cheap)
__global__ void transpose_wq_kernel(const float* __restrict__ Wq, float* __restrict__ WqT) {
  int idx = blockIdx.x * 256 + threadIdx.x;  // over 640*256
  int d = idx & (D - 1);
  int k = idx >> 8;
  WqT[idx] = Wq[d * QIN + k];
}

// SW = 256: W points at WqT (stride-256 along k, coalesced across d)
// SW = 1  : W points at Wq  (fallback, stride-1 along k per thread)
template <int SW>
__global__ __launch_bounds__(256, 2) void fused_kernel(
    const float* __restrict__ raw, const float* __restrict__ edge,
    const float* __restrict__ tim, const float* __restrict__ proto,
    const float* __restrict__ W, const float* __restrict__ bq,
    const float* __restrict__ Wg, const float* __restrict__ bg,
    const float* __restrict__ temp, const float* __restrict__ lnw,
    const float* __restrict__ lnb, float* __restrict__ out) {
  __shared__ float qin[R][QIN];   // 40 KB: [raw | edge | time] per row
  __shared__ float qpre[R][D];    // 16 KB: GEMM result

  const int tid = threadIdx.x;
  const int r0 = blockIdx.x * R;

  // ---- stage q_in rows into LDS (coalesced) ----
#pragma unroll
  for (int r = 0; r < R; ++r) {
    const size_t g = (size_t)(r0 + r);
    qin[r][tid]     = raw[g * D + tid];
    qin[r][D + tid] = edge[g * E + tid];
    if (tid < T) qin[r][D + E + tid] = tim[g * T + tid];
  }
  __syncthreads();

  // ---- GEMM: qpre[r][d] = q_in[r][:] . Wq[d][:] + bq[d] ----
  {
    const float* wcol = (SW == 1) ? (W + (size_t)tid * QIN) : (W + tid);
    const float bqv = bq[tid];
    float acc[R];
#pragma unroll
    for (int r = 0; r < R; ++r) acc[r] = bqv;
    for (int k = 0; k < QIN; k += 4) {
      const float w0 = wcol[(size_t)(k + 0) * SW];
      const float w1 = wcol[(size_t)(k + 1) * SW];
      const float w2 = wcol[(size_t)(k + 2) * SW];
      const float w3 = wcol[(size_t)(k + 3) * SW];
#pragma unroll
      for (int r = 0; r < R; ++r) {
        const float4 q4 = *(const float4*)&qin[r][k];  // LDS broadcast
        float a = acc[r];
        a = fmaf(q4.x, w0, a);
        a = fmaf(q4.y, w1, a);
        a = fmaf(q4.z, w2, a);
        a = fmaf(q4.w, w3, a);
        acc[r] = a;
      }
    }
#pragma unroll
    for (int r = 0; r < R; ++r) qpre[r][tid] = acc[r];
  }
  __syncthreads();

  // ---- epilogue: one wave per row; lane owns dims 4*lane..4*lane+3 ----
  const int wv = tid >> 6;
  const int lane = tid & 63;
  const float4 lnw4 = *(const float4*)(lnw + 4 * lane);
  const float4 lnb4 = *(const float4*)(lnb + 4 * lane);
  const float lw[4] = {lnw4.x, lnw4.y, lnw4.z, lnw4.w};
  const float lb[4] = {lnb4.x, lnb4.y, lnb4.z, lnb4.w};
  const float4 wga = *(const float4*)(Wg + 4 * lane);
  const float4 wgb = *(const float4*)(Wg + D + 4 * lane);
  const float2 wgt = *(const float2*)(Wg + 2 * D + 2 * lane);
  const float bgv = bg[0];
  const float invt = 1.0f / (clampf(temp[0], 0.5f, 5.0f) + 0.01f);

  for (int r = wv; r < R; r += 4) {
    const size_t g = (size_t)(r0 + r);

    // LayerNorm + tanh -> query
    const float4 x4 = *(const float4*)&qpre[r][4 * lane];
    float x[4] = {x4.x, x4.y, x4.z, x4.w};
    float s = x[0] + x[1] + x[2] + x[3];
    const float mu = wsum(s) * (1.0f / 256.0f);
    float dx[4];
    float v = 0.f;
#pragma unroll
    for (int i = 0; i < 4; ++i) { dx[i] = x[i] - mu; v += dx[i] * dx[i]; }
    const float rstd = 1.0f / sqrtf(wsum(v) * (1.0f / 256.0f) + 1e-6f);
    float q[4];
    float qs = 0.f;
#pragma unroll
    for (int i = 0; i < 4; ++i) {
      q[i] = tanhf(dx[i] * rstd * lw[i] + lb[i]);
      qs += q[i] * q[i];
    }
    const float qdiv = fmaxf(sqrtf(wsum(qs)), 1e-6f);

    // cosine sim vs prototypes; keep prototype values in registers
    const float* pb = proto + (g * P) * D + 4 * lane;
    float pv[P][4];
    float sim[P];
#pragma unroll
    for (int p = 0; p < P; ++p) {
      const float4 p4 = *(const float4*)(pb + (size_t)p * D);
      pv[p][0] = p4.x; pv[p][1] = p4.y; pv[p][2] = p4.z; pv[p][3] = p4.w;
      float dt = q[0] * p4.x + q[1] * p4.y + q[2] * p4.z + q[3] * p4.w;
      float pn = p4.x * p4.x + p4.y * p4.y + p4.z * p4.z + p4.w * p4.w;
      wsum2(dt, pn);
      const float pdiv = fmaxf(sqrtf(pn), 1e-6f);
      sim[p] = clampf(dt / (qdiv * pdiv), -10.0f, 10.0f) * invt;
    }

    // softmax over P (redundant per lane; cheap)
    float m = sim[0];
#pragma unroll
    for (int p = 1; p < P; ++p) m = fmaxf(m, sim[p]);
    float es[P];
    float ssum = 0.f;
#pragma unroll
    for (int p = 0; p < P; ++p) { es[p] = expf(sim[p] - m); ssum += es[p]; }
    const float sinv = 1.0f / ssum;
    float cand[4] = {0.f, 0.f, 0.f, 0.f};
#pragma unroll
    for (int p = 0; p < P; ++p) {
      const float a = clampf(es[p] * sinv, 0.0f, 1.0f);
#pragma unroll
      for (int i = 0; i < 4; ++i) cand[i] = fmaf(a, pv[p][i], cand[i]);
    }
#pragma unroll
    for (int i = 0; i < 4; ++i) cand[i] = clampf(cand[i], -5.0f, 5.0f);

    // gate = sigmoid(clip(g_in . Wg + bg, +-10)), g_in clipped +-50
    const float4 raw4 = *(const float4*)&qin[r][4 * lane];
    const float rr[4] = {raw4.x, raw4.y, raw4.z, raw4.w};
    const float2 t2 = *(const float2*)&qin[r][2 * D + 2 * lane];
    float gsum =
        clampf(rr[0], -50.f, 50.f) * wga.x + clampf(rr[1], -50.f, 50.f) * wga.y +
        clampf(rr[2], -50.f, 50.f) * wga.z + clampf(rr[3], -50.f, 50.f) * wga.w +
        clampf(cand[0], -50.f, 50.f) * wgb.x + clampf(cand[1], -50.f, 50.f) * wgb.y +
        clampf(cand[2], -50.f, 50.f) * wgb.z + clampf(cand[3], -50.f, 50.f) * wgb.w +
        clampf(t2.x, -50.f, 50.f) * wgt.x + clampf(t2.y, -50.f, 50.f) * wgt.y;
    const float z = clampf(wsum(gsum) + bgv, -10.0f, 10.0f);
    const float gate = 1.0f / (1.0f + expf(-z));

    // gated update + final LN + clip
    float upd[4];
    float s2 = 0.f;
#pragma unroll
    for (int i = 0; i < 4; ++i) {
      upd[i] = (1.0f - gate) * rr[i] + gate * cand[i];
      s2 += upd[i];
    }
    const float mu2 = wsum(s2) * (1.0f / 256.0f);
    float du[4];
    float v2 = 0.f;
#pragma unroll
    for (int i = 0; i < 4; ++i) { du[i] = upd[i] - mu2; v2 += du[i] * du[i]; }
    const float rstd2 = 1.0f / sqrtf(wsum(v2) * (1.0f / 256.0f) + 1e-6f);
    float4 y;
    y.x = clampf(du[0] * rstd2 * lw[0] + lb[0], -10.0f, 10.0f);
    y.y = clampf(du[1] * rstd2 * lw[1] + lb[1], -10.0f, 10.0f);
    y.z = clampf(du[2] * rstd2 * lw[2] + lb[2], -10.0f, 10.0f);
    y.w = clampf(du[3] * rstd2 * lw[3] + lb[3], -10.0f, 10.0f);
    *(float4*)(out + g * D + 4 * lane) = y;
  }
}

extern "C" void kernel_launch(void* const* d_in, const int* in_sizes, int n_in,
                              void* d_out, int out_size, void* d_ws, size_t ws_size,
                              hipStream_t stream) {
  const float* raw   = (const float*)d_in[0];
  // d_in[1] = node_features: unused by the reference
  const float* edge  = (const float*)d_in[2];
  const float* tim   = (const float*)d_in[3];
  const float* proto = (const float*)d_in[4];
  const float* Wq    = (const float*)d_in[5];
  const float* bq    = (const float*)d_in[6];
  const float* Wg    = (const float*)d_in[7];
  const float* bg    = (const float*)d_in[8];
  const float* temp  = (const float*)d_in[9];
  const float* lnw   = (const float*)d_in[10];
  const float* lnb   = (const float*)d_in[11];
  float* out = (float*)d_out;

  const int B = in_sizes[0] / D;
  const int nblk = B / R;

  const bool use_wt = ws_size >= (size_t)(QIN * D * sizeof(float));
  if (use_wt) {
    float* WqT = (float*)d_ws;
    transpose_wq_kernel<<<(QIN * D) / 256, 256, 0, stream>>>(Wq, WqT);
    fused_kernel<D><<<nblk, 256, 0, stream>>>(raw, edge, tim, proto, WqT, bq, Wg,
                                              bg, temp, lnw, lnb, out);
  } else {
    fused_kernel<1><<<nblk, 256, 0, stream>>>(raw, edge, tim, proto, Wq, bq, Wg,
                                              bg, temp, lnw, lnb, out);
  }
}

// Round 2
// 227.134 us; speedup vs baseline: 3.5262x; 3.5262x over previous
//
#include <hip/hip_runtime.h>
#include <cstdint>
#include <cstddef>

#define D 256
#define E 256
#define T 128
#define QIN 640   // D + E + T
#define P 8
#define R 16      // batch rows per block
#define KP 648    // qa row stride in ushort (pad: 648*2=1296B, 1296%128=16 -> rows shift banks)
#define DP 260    // qpre row stride in floats

typedef __attribute__((ext_vector_type(8))) short bf16x8;
typedef __attribute__((ext_vector_type(4))) float f32x4;

__device__ __forceinline__ ushort f2bf(float f) {   // RNE fp32->bf16
  uint32_t u = __float_as_uint(f);
  u += 0x7fffu + ((u >> 16) & 1u);
  return (ushort)(u >> 16);
}

__device__ __forceinline__ float wsum(float v) {
#pragma unroll
  for (int o = 32; o > 0; o >>= 1) v += __shfl_xor(v, o, 64);
  return v;
}

__device__ __forceinline__ void wsum2(float& a, float& b) {
#pragma unroll
  for (int o = 32; o > 0; o >>= 1) {
    a += __shfl_xor(a, o, 64);
    b += __shfl_xor(b, o, 64);
  }
}

__device__ __forceinline__ float clampf(float x, float lo, float hi) {
  return fminf(fmaxf(x, lo), hi);
}

// W2[((k>>3)*D + n)*8 + (k&7)] = bf16(Wq[n][k])  -- fragment-friendly layout:
// B-frag for col n, k-base kb, lane l reads 8 contiguous bf16 at ((kb>>3)+(l>>4))*D + n.
__global__ void prep_w2_kernel(const float* __restrict__ Wq, ushort* __restrict__ W2) {
  const int idx = blockIdx.x * 256 + threadIdx.x;  // over D*QIN, coalesced read
  const int n = idx / QIN;
  const int k = idx - n * QIN;
  W2[((((k >> 3) * D + n) << 3)) + (k & 7)] = f2bf(Wq[idx]);
}

// PRE=true: B-fragments from pre-packed bf16 W2 (one dwordx4 per frag).
// PRE=false: B-fragments from fp32 Wq rows, converted in-register.
template <bool PRE>
__global__ __launch_bounds__(256, 4) void fused_kernel(
    const float* __restrict__ raw, const float* __restrict__ edge,
    const float* __restrict__ tim, const float* __restrict__ proto,
    const float* __restrict__ Wq, const ushort* __restrict__ W2,
    const float* __restrict__ bq, const float* __restrict__ Wg,
    const float* __restrict__ bg, const float* __restrict__ temp,
    const float* __restrict__ lnw, const float* __restrict__ lnb,
    float* __restrict__ out) {
  __shared__ ushort qa[R][KP];    // 20.25 KB: bf16 [raw|edge|time] per row
  __shared__ float qpre[R][DP];   // 16.25 KB: GEMM result (pre-LN)

  const int tid = threadIdx.x;
  const int r0 = blockIdx.x * R;

  // ---- stage q_in rows -> bf16 LDS (coalesced float4 reads) ----
#pragma unroll
  for (int it = 0; it < (R * QIN / 4) / 256; ++it) {
    const int flat = it * 256 + tid;        // 0..2559 chunk id (4 floats each)
    const int r = flat / (QIN / 4);
    const int p4 = (flat - r * (QIN / 4)) * 4;
    const size_t g = (size_t)(r0 + r);
    float4 v;
    if (p4 < D)          v = *(const float4*)(raw + g * D + p4);
    else if (p4 < D + E) v = *(const float4*)(edge + g * E + (p4 - D));
    else                 v = *(const float4*)(tim + g * T + (p4 - D - E));
    ushort4 h;
    h.x = f2bf(v.x); h.y = f2bf(v.y); h.z = f2bf(v.z); h.w = f2bf(v.w);
    *(ushort4*)&qa[r][p4] = h;              // 8B ds_write
  }
  __syncthreads();

  const int w = tid >> 6;
  const int lane = tid & 63;
  const int lr = lane & 15;   // A-row / C-col within tile
  const int lh = lane >> 4;   // k-group 0..3

  // ---- GEMM: 4 waves x 4 col-tiles of 16, K=640 in steps of 32 ----
  {
    f32x4 acc[4];
#pragma unroll
    for (int c = 0; c < 4; ++c) acc[c] = (f32x4){0.f, 0.f, 0.f, 0.f};

    for (int kb = 0; kb < QIN; kb += 32) {
      const bf16x8 af = *(const bf16x8*)&qa[lr][kb + lh * 8];  // ds_read_b128
#pragma unroll
      for (int c = 0; c < 4; ++c) {
        const int n = w * 64 + c * 16 + lr;
        bf16x8 bfv;
        if (PRE) {
          bfv = *(const bf16x8*)&W2[(((kb >> 3) + lh) * D + n) << 3];
        } else {
          const float* src = Wq + (size_t)n * QIN + kb + lh * 8;
          const float4 a0 = *(const float4*)src;
          const float4 a1 = *(const float4*)(src + 4);
          bfv[0] = (short)f2bf(a0.x); bfv[1] = (short)f2bf(a0.y);
          bfv[2] = (short)f2bf(a0.z); bfv[3] = (short)f2bf(a0.w);
          bfv[4] = (short)f2bf(a1.x); bfv[5] = (short)f2bf(a1.y);
          bfv[6] = (short)f2bf(a1.z); bfv[7] = (short)f2bf(a1.w);
        }
        acc[c] = __builtin_amdgcn_mfma_f32_16x16x32_bf16(af, bfv, acc[c], 0, 0, 0);
      }
    }

    // C/D layout (m89-verified): col = lane&15, row = (lane>>4)*4 + reg
#pragma unroll
    for (int c = 0; c < 4; ++c) {
      const int n = w * 64 + c * 16 + lr;
      const float bqv = bq[n];
#pragma unroll
      for (int i = 0; i < 4; ++i) qpre[lh * 4 + i][n] = acc[c][i] + bqv;
    }
  }
  __syncthreads();

  // ---- epilogue: one wave per row; lane owns dims 4*lane..4*lane+3 ----
  const float4 lnw4 = *(const float4*)(lnw + 4 * lane);
  const float4 lnb4 = *(const float4*)(lnb + 4 * lane);
  const float lw[4] = {lnw4.x, lnw4.y, lnw4.z, lnw4.w};
  const float lb[4] = {lnb4.x, lnb4.y, lnb4.z, lnb4.w};
  const float4 wga = *(const float4*)(Wg + 4 * lane);
  const float4 wgb = *(const float4*)(Wg + D + 4 * lane);
  const float2 wgt = *(const float2*)(Wg + 2 * D + 2 * lane);
  const float bgv = bg[0];
  const float invt = 1.0f / (clampf(temp[0], 0.5f, 5.0f) + 0.01f);

  for (int r = w; r < R; r += 4) {
    const size_t g = (size_t)(r0 + r);

    // LayerNorm + tanh -> query
    const float4 x4 = *(const float4*)&qpre[r][4 * lane];
    float x[4] = {x4.x, x4.y, x4.z, x4.w};
    float s = x[0] + x[1] + x[2] + x[3];
    const float mu = wsum(s) * (1.0f / 256.0f);
    float dx[4];
    float v = 0.f;
#pragma unroll
    for (int i = 0; i < 4; ++i) { dx[i] = x[i] - mu; v += dx[i] * dx[i]; }
    const float rstd = 1.0f / sqrtf(wsum(v) * (1.0f / 256.0f) + 1e-6f);
    float q[4];
    float qs = 0.f;
#pragma unroll
    for (int i = 0; i < 4; ++i) {
      q[i] = tanhf(dx[i] * rstd * lw[i] + lb[i]);
      qs += q[i] * q[i];
    }
    const float qdiv = fmaxf(sqrtf(wsum(qs)), 1e-6f);

    // cosine sim vs prototypes; prototype values stay in registers
    const float* pb = proto + (g * P) * D + 4 * lane;
    float pv[P][4];
    float sim[P];
#pragma unroll
    for (int p = 0; p < P; ++p) {
      const float4 p4 = *(const float4*)(pb + (size_t)p * D);
      pv[p][0] = p4.x; pv[p][1] = p4.y; pv[p][2] = p4.z; pv[p][3] = p4.w;
      float dt = q[0] * p4.x + q[1] * p4.y + q[2] * p4.z + q[3] * p4.w;
      float pn = p4.x * p4.x + p4.y * p4.y + p4.z * p4.z + p4.w * p4.w;
      wsum2(dt, pn);
      const float pdiv = fmaxf(sqrtf(pn), 1e-6f);
      sim[p] = clampf(dt / (qdiv * pdiv), -10.0f, 10.0f) * invt;
    }

    // softmax over P (redundant per lane; cheap)
    float m = sim[0];
#pragma unroll
    for (int p = 1; p < P; ++p) m = fmaxf(m, sim[p]);
    float es[P];
    float ssum = 0.f;
#pragma unroll
    for (int p = 0; p < P; ++p) { es[p] = expf(sim[p] - m); ssum += es[p]; }
    const float sinv = 1.0f / ssum;
    float cand[4] = {0.f, 0.f, 0.f, 0.f};
#pragma unroll
    for (int p = 0; p < P; ++p) {
      const float a = clampf(es[p] * sinv, 0.0f, 1.0f);
#pragma unroll
      for (int i = 0; i < 4; ++i) cand[i] = fmaf(a, pv[p][i], cand[i]);
    }
#pragma unroll
    for (int i = 0; i < 4; ++i) cand[i] = clampf(cand[i], -5.0f, 5.0f);

    // gate = sigmoid(clip(g_in . Wg + bg, +-10)), g_in clipped +-50
    const float4 raw4 = *(const float4*)(raw + g * D + 4 * lane);  // L2-warm
    const float rr[4] = {raw4.x, raw4.y, raw4.z, raw4.w};
    const float2 t2 = *(const float2*)(tim + g * T + 2 * lane);
    float gsum =
        clampf(rr[0], -50.f, 50.f) * wga.x + clampf(rr[1], -50.f, 50.f) * wga.y +
        clampf(rr[2], -50.f, 50.f) * wga.z + clampf(rr[3], -50.f, 50.f) * wga.w +
        clampf(cand[0], -50.f, 50.f) * wgb.x + clampf(cand[1], -50.f, 50.f) * wgb.y +
        clampf(cand[2], -50.f, 50.f) * wgb.z + clampf(cand[3], -50.f, 50.f) * wgb.w +
        clampf(t2.x, -50.f, 50.f) * wgt.x + clampf(t2.y, -50.f, 50.f) * wgt.y;
    const float z = clampf(wsum(gsum) + bgv, -10.0f, 10.0f);
    const float gate = 1.0f / (1.0f + expf(-z));

    // gated update + final LN + clip
    float upd[4];
    float s2 = 0.f;
#pragma unroll
    for (int i = 0; i < 4; ++i) {
      upd[i] = (1.0f - gate) * rr[i] + gate * cand[i];
      s2 += upd[i];
    }
    const float mu2 = wsum(s2) * (1.0f / 256.0f);
    float du[4];
    float v2 = 0.f;
#pragma unroll
    for (int i = 0; i < 4; ++i) { du[i] = upd[i] - mu2; v2 += du[i] * du[i]; }
    const float rstd2 = 1.0f / sqrtf(wsum(v2) * (1.0f / 256.0f) + 1e-6f);
    float4 y;
    y.x = clampf(du[0] * rstd2 * lw[0] + lb[0], -10.0f, 10.0f);
    y.y = clampf(du[1] * rstd2 * lw[1] + lb[1], -10.0f, 10.0f);
    y.z = clampf(du[2] * rstd2 * lw[2] + lb[2], -10.0f, 10.0f);
    y.w = clampf(du[3] * rstd2 * lw[3] + lb[3], -10.0f, 10.0f);
    *(float4*)(out + g * D + 4 * lane) = y;
  }
}

extern "C" void kernel_launch(void* const* d_in, const int* in_sizes, int n_in,
                              void* d_out, int out_size, void* d_ws, size_t ws_size,
                              hipStream_t stream) {
  const float* raw   = (const float*)d_in[0];
  // d_in[1] = node_features: unused by the reference
  const float* edge  = (const float*)d_in[2];
  const float* tim   = (const float*)d_in[3];
  const float* proto = (const float*)d_in[4];
  const float* Wq    = (const float*)d_in[5];
  const float* bq    = (const float*)d_in[6];
  const float* Wg    = (const float*)d_in[7];
  const float* bg    = (const float*)d_in[8];
  const float* temp  = (const float*)d_in[9];
  const float* lnw   = (const float*)d_in[10];
  const float* lnb   = (const float*)d_in[11];
  float* out = (float*)d_out;

  const int B = in_sizes[0] / D;
  const int nblk = B / R;

  const bool pre = ws_size >= (size_t)(QIN * D * sizeof(ushort));
  if (pre) {
    ushort* W2 = (ushort*)d_ws;
    prep_w2_kernel<<<(QIN * D) / 256, 256, 0, stream>>>(Wq, W2);
    fused_kernel<true><<<nblk, 256, 0, stream>>>(raw, edge, tim, proto, Wq, W2,
                                                 bq, Wg, bg, temp, lnw, lnb, out);
  } else {
    fused_kernel<false><<<nblk, 256, 0, stream>>>(raw, edge, tim, proto, Wq,
                                                  (const ushort*)nullptr, bq, Wg,
                                                  bg, temp, lnw, lnb, out);
  }
}

// Round 3
// 220.207 us; speedup vs baseline: 3.6372x; 1.0315x over previous
//
#include <hip/hip_runtime.h>
#include <cstdint>
#include <cstddef>

#define D 256
#define E 256
#define T 128
#define QIN 640   // D + E + T
#define P 8
#define R 16      // batch rows per block
#define KP 648    // qa row stride in ushort
#define DP 260    // qpre row stride in floats

typedef __attribute__((ext_vector_type(8))) short bf16x8;
typedef __attribute__((ext_vector_type(4))) float f32x4;

__device__ __forceinline__ ushort f2bf(float f) {   // RNE fp32->bf16
  uint32_t u = __float_as_uint(f);
  u += 0x7fffu + ((u >> 16) & 1u);
  return (ushort)(u >> 16);
}

__device__ __forceinline__ float wsum(float v) {
#pragma unroll
  for (int o = 32; o > 0; o >>= 1) v += __shfl_xor(v, o, 64);
  return v;
}

__device__ __forceinline__ void wsum2(float& a, float& b) {
#pragma unroll
  for (int o = 32; o > 0; o >>= 1) {
    a += __shfl_xor(a, o, 64);
    b += __shfl_xor(b, o, 64);
  }
}

__device__ __forceinline__ float clampf(float x, float lo, float hi) {
  return fminf(fmaxf(x, lo), hi);
}

// W2[((k>>3)*D + n)*8 + (k&7)] = bf16(Wq[n][k])
__global__ void prep_w2_kernel(const float* __restrict__ Wq, ushort* __restrict__ W2) {
  const int idx = blockIdx.x * 256 + threadIdx.x;  // over D*QIN, coalesced read
  const int n = idx / QIN;
  const int k = idx - n * QIN;
  W2[((((k >> 3) * D + n) << 3)) + (k & 7)] = f2bf(Wq[idx]);
}

template <bool PRE>
__global__ __launch_bounds__(256, 4) void fused_kernel(
    const float* __restrict__ raw, const float* __restrict__ edge,
    const float* __restrict__ tim, const float* __restrict__ proto,
    const float* __restrict__ Wq, const ushort* __restrict__ W2,
    const float* __restrict__ bq, const float* __restrict__ Wg,
    const float* __restrict__ bg, const float* __restrict__ temp,
    const float* __restrict__ lnw, const float* __restrict__ lnb,
    float* __restrict__ out) {
  __shared__ ushort qa[R][KP];    // 20.25 KB: bf16 [raw|edge|time] per row
  __shared__ float qpre[R][DP];   // 16.25 KB: GEMM result (pre-LN)

  const int tid = threadIdx.x;
  const int r0 = blockIdx.x * R;

  // ---- stage q_in rows -> bf16 LDS (coalesced float4 reads) ----
#pragma unroll
  for (int it = 0; it < (R * QIN / 4) / 256; ++it) {
    const int flat = it * 256 + tid;
    const int r = flat / (QIN / 4);
    const int p4 = (flat - r * (QIN / 4)) * 4;
    const size_t g = (size_t)(r0 + r);
    float4 v;
    if (p4 < D)          v = *(const float4*)(raw + g * D + p4);
    else if (p4 < D + E) v = *(const float4*)(edge + g * E + (p4 - D));
    else                 v = *(const float4*)(tim + g * T + (p4 - D - E));
    ushort4 h;
    h.x = f2bf(v.x); h.y = f2bf(v.y); h.z = f2bf(v.z); h.w = f2bf(v.w);
    *(ushort4*)&qa[r][p4] = h;
  }
  __syncthreads();

  const int w = tid >> 6;
  const int lane = tid & 63;
  const int lr = lane & 15;   // A-row / C-col within tile
  const int lh = lane >> 4;   // k-group 0..3

  // ---- prefetch row (r0+w) protos: latency hides under entire GEMM ----
  float4 bufA[P], bufB[P];
  {
    const float* pb0 = proto + ((size_t)(r0 + w) * P) * D + 4 * lane;
#pragma unroll
    for (int p = 0; p < P; ++p) bufA[p] = *(const float4*)(pb0 + (size_t)p * D);
  }

  // ---- GEMM: 4 waves x 4 col-tiles of 16, K=640 in steps of 32 ----
  {
    f32x4 acc[4];
#pragma unroll
    for (int c = 0; c < 4; ++c) acc[c] = (f32x4){0.f, 0.f, 0.f, 0.f};

    for (int kb = 0; kb < QIN; kb += 32) {
      const bf16x8 af = *(const bf16x8*)&qa[lr][kb + lh * 8];  // ds_read_b128
#pragma unroll
      for (int c = 0; c < 4; ++c) {
        const int n = w * 64 + c * 16 + lr;
        bf16x8 bfv;
        if (PRE) {
          bfv = *(const bf16x8*)&W2[(((kb >> 3) + lh) * D + n) << 3];
        } else {
          const float* src = Wq + (size_t)n * QIN + kb + lh * 8;
          const float4 a0 = *(const float4*)src;
          const float4 a1 = *(const float4*)(src + 4);
          bfv[0] = (short)f2bf(a0.x); bfv[1] = (short)f2bf(a0.y);
          bfv[2] = (short)f2bf(a0.z); bfv[3] = (short)f2bf(a0.w);
          bfv[4] = (short)f2bf(a1.x); bfv[5] = (short)f2bf(a1.y);
          bfv[6] = (short)f2bf(a1.z); bfv[7] = (short)f2bf(a1.w);
        }
        acc[c] = __builtin_amdgcn_mfma_f32_16x16x32_bf16(af, bfv, acc[c], 0, 0, 0);
      }
    }

    // C/D layout: col = lane&15, row = (lane>>4)*4 + reg
#pragma unroll
    for (int c = 0; c < 4; ++c) {
      const int n = w * 64 + c * 16 + lr;
      const float bqv = bq[n];
#pragma unroll
      for (int i = 0; i < 4; ++i) qpre[lh * 4 + i][n] = acc[c][i] + bqv;
    }
  }
  __syncthreads();

  // ---- epilogue consts ----
  const float4 lnw4 = *(const float4*)(lnw + 4 * lane);
  const float4 lnb4 = *(const float4*)(lnb + 4 * lane);
  const float lw[4] = {lnw4.x, lnw4.y, lnw4.z, lnw4.w};
  const float lb[4] = {lnb4.x, lnb4.y, lnb4.z, lnb4.w};
  const float4 wga = *(const float4*)(Wg + 4 * lane);
  const float4 wgb = *(const float4*)(Wg + D + 4 * lane);
  const float2 wgt = *(const float2*)(Wg + 2 * D + 2 * lane);
  const float bgv = bg[0];
  const float invt = 1.0f / (clampf(temp[0], 0.5f, 5.0f) + 0.01f);

  // one wave per row; lane owns dims 4*lane..4*lane+3; double-buffered protos
  auto process = [&](int r, float4* cur, float4* nxt, bool pre) {
    const size_t g = (size_t)(r0 + r);

    // prefetch next row's protos (in flight during this row's whole chain)
    if (pre) {
      const float* pbn = proto + ((g + 4) * P) * D + 4 * lane;
#pragma unroll
      for (int p = 0; p < P; ++p) nxt[p] = *(const float4*)(pbn + (size_t)p * D);
    }
    // gate inputs needed mid-chain; issue now (L2-warm)
    const float4 raw4 = *(const float4*)(raw + g * D + 4 * lane);
    const float2 t2 = *(const float2*)(tim + g * T + 2 * lane);

    // LayerNorm + tanh -> query
    const float4 x4 = *(const float4*)&qpre[r][4 * lane];
    float x[4] = {x4.x, x4.y, x4.z, x4.w};
    float s = x[0] + x[1] + x[2] + x[3];
    const float mu = wsum(s) * (1.0f / 256.0f);
    float dx[4];
    float v = 0.f;
#pragma unroll
    for (int i = 0; i < 4; ++i) { dx[i] = x[i] - mu; v += dx[i] * dx[i]; }
    const float rstd = 1.0f / sqrtf(wsum(v) * (1.0f / 256.0f) + 1e-6f);
    float q[4];
    float qs = 0.f;
#pragma unroll
    for (int i = 0; i < 4; ++i) {
      q[i] = tanhf(dx[i] * rstd * lw[i] + lb[i]);
      qs += q[i] * q[i];
    }
    const float qdiv = fmaxf(sqrtf(wsum(qs)), 1e-6f);

    // cosine sim vs prototypes (cur[] landed long ago)
    float sim[P];
#pragma unroll
    for (int p = 0; p < P; ++p) {
      const float4 p4 = cur[p];
      float dt = q[0] * p4.x + q[1] * p4.y + q[2] * p4.z + q[3] * p4.w;
      float pn = p4.x * p4.x + p4.y * p4.y + p4.z * p4.z + p4.w * p4.w;
      wsum2(dt, pn);
      const float pdiv = fmaxf(sqrtf(pn), 1e-6f);
      sim[p] = clampf(dt / (qdiv * pdiv), -10.0f, 10.0f) * invt;
    }

    // softmax over P (redundant per lane; cheap)
    float m = sim[0];
#pragma unroll
    for (int p = 1; p < P; ++p) m = fmaxf(m, sim[p]);
    float ssum = 0.f;
#pragma unroll
    for (int p = 0; p < P; ++p) { sim[p] = expf(sim[p] - m); ssum += sim[p]; }
    const float sinv = 1.0f / ssum;
    float cand[4] = {0.f, 0.f, 0.f, 0.f};
#pragma unroll
    for (int p = 0; p < P; ++p) {
      const float a = clampf(sim[p] * sinv, 0.0f, 1.0f);
      cand[0] = fmaf(a, cur[p].x, cand[0]);
      cand[1] = fmaf(a, cur[p].y, cand[1]);
      cand[2] = fmaf(a, cur[p].z, cand[2]);
      cand[3] = fmaf(a, cur[p].w, cand[3]);
    }
#pragma unroll
    for (int i = 0; i < 4; ++i) cand[i] = clampf(cand[i], -5.0f, 5.0f);

    // gate = sigmoid(clip(g_in . Wg + bg, +-10)), g_in clipped +-50
    const float rr[4] = {raw4.x, raw4.y, raw4.z, raw4.w};
    float gsum =
        clampf(rr[0], -50.f, 50.f) * wga.x + clampf(rr[1], -50.f, 50.f) * wga.y +
        clampf(rr[2], -50.f, 50.f) * wga.z + clampf(rr[3], -50.f, 50.f) * wga.w +
        clampf(cand[0], -50.f, 50.f) * wgb.x + clampf(cand[1], -50.f, 50.f) * wgb.y +
        clampf(cand[2], -50.f, 50.f) * wgb.z + clampf(cand[3], -50.f, 50.f) * wgb.w +
        clampf(t2.x, -50.f, 50.f) * wgt.x + clampf(t2.y, -50.f, 50.f) * wgt.y;
    const float z = clampf(wsum(gsum) + bgv, -10.0f, 10.0f);
    const float gate = 1.0f / (1.0f + expf(-z));

    // gated update + final LN + clip
    float upd[4];
    float s2 = 0.f;
#pragma unroll
    for (int i = 0; i < 4; ++i) {
      upd[i] = (1.0f - gate) * rr[i] + gate * cand[i];
      s2 += upd[i];
    }
    const float mu2 = wsum(s2) * (1.0f / 256.0f);
    float du[4];
    float v2 = 0.f;
#pragma unroll
    for (int i = 0; i < 4; ++i) { du[i] = upd[i] - mu2; v2 += du[i] * du[i]; }
    const float rstd2 = 1.0f / sqrtf(wsum(v2) * (1.0f / 256.0f) + 1e-6f);
    float4 y;
    y.x = clampf(du[0] * rstd2 * lw[0] + lb[0], -10.0f, 10.0f);
    y.y = clampf(du[1] * rstd2 * lw[1] + lb[1], -10.0f, 10.0f);
    y.z = clampf(du[2] * rstd2 * lw[2] + lb[2], -10.0f, 10.0f);
    y.w = clampf(du[3] * rstd2 * lw[3] + lb[3], -10.0f, 10.0f);
    *(float4*)(out + g * D + 4 * lane) = y;
  };

  process(w,      bufA, bufB, true);
  process(w + 4,  bufB, bufA, true);
  process(w + 8,  bufA, bufB, true);
  process(w + 12, bufB, bufA, false);
}

extern "C" void kernel_launch(void* const* d_in, const int* in_sizes, int n_in,
                              void* d_out, int out_size, void* d_ws, size_t ws_size,
                              hipStream_t stream) {
  const float* raw   = (const float*)d_in[0];
  // d_in[1] = node_features: unused by the reference
  const float* edge  = (const float*)d_in[2];
  const float* tim   = (const float*)d_in[3];
  const float* proto = (const float*)d_in[4];
  const float* Wq    = (const float*)d_in[5];
  const float* bq    = (const float*)d_in[6];
  const float* Wg    = (const float*)d_in[7];
  const float* bg    = (const float*)d_in[8];
  const float* temp  = (const float*)d_in[9];
  const float* lnw   = (const float*)d_in[10];
  const float* lnb   = (const float*)d_in[11];
  float* out = (float*)d_out;

  const int B = in_sizes[0] / D;
  const int nblk = B / R;

  const bool pre = ws_size >= (size_t)(QIN * D * sizeof(ushort));
  if (pre) {
    ushort* W2 = (ushort*)d_ws;
    prep_w2_kernel<<<(QIN * D) / 256, 256, 0, stream>>>(Wq, W2);
    fused_kernel<true><<<nblk, 256, 0, stream>>>(raw, edge, tim, proto, Wq, W2,
                                                 bq, Wg, bg, temp, lnw, lnb, out);
  } else {
    fused_kernel<false><<<nblk, 256, 0, stream>>>(raw, edge, tim, proto, Wq,
                                                  (const ushort*)nullptr, bq, Wg,
                                                  bg, temp, lnw, lnb, out);
  }
}